// Round 2
// baseline (765.259 us; speedup 1.0000x reference)
//
#include <hip/hip_runtime.h>
#include <hip/hip_bf16.h>

// MoE top-2 of 8 experts. T=8192 tokens, D=1024, H=4096.
// route(+cast x) -> scan -> scatter -> transpose w1,w2 -> GEMM1(relu) -> GEMM2(scatter-add)
// GEMMs: 256x256xBK64 tile, 8 waves, minimum-2-phase prefetch (T3 recipe),
// both-sides XOR swizzle (T2), expert-major bijective XCD swizzle (T1).

#define T_TOK   8192
#define DIM     1024
#define NEXP    8
#define HID     4096

typedef unsigned short ushort_t;
typedef __attribute__((ext_vector_type(8))) short bfrag;
typedef __attribute__((ext_vector_type(4))) float f32x4;

__device__ __forceinline__ ushort_t f2bf(float f) {
    union { float f; unsigned int u; } v; v.f = f;
    unsigned int r = v.u + 0x7FFFu + ((v.u >> 16) & 1u);
    return (ushort_t)(r >> 16);
}

__device__ __forceinline__ void async_load16(const void* g, void* l) {
    __builtin_amdgcn_global_load_lds(
        (const __attribute__((address_space(1))) unsigned int*)g,
        (__attribute__((address_space(3))) unsigned int*)l, 16, 0, 0);
}

// ---------------- routing ----------------
__global__ __launch_bounds__(256)
void route_kern(const float* __restrict__ x, const float* __restrict__ wg,
                ushort_t* __restrict__ x_bf, int* __restrict__ topk,
                float* __restrict__ gates, int* __restrict__ counts)
{
    const int w = threadIdx.x >> 6, lane = threadIdx.x & 63;
    const int t = blockIdx.x * 4 + w;
    const float* xr = x + (size_t)t * DIM;
    float acc[8];
#pragma unroll
    for (int e = 0; e < 8; ++e) acc[e] = 0.f;

#pragma unroll
    for (int it = 0; it < 4; ++it) {
        const int j = it * 256 + lane * 4;
        float4 xv = *(const float4*)(xr + j);
        ushort4 xb;
        xb.x = f2bf(xv.x); xb.y = f2bf(xv.y); xb.z = f2bf(xv.z); xb.w = f2bf(xv.w);
        *(ushort4*)(x_bf + (size_t)t * DIM + j) = xb;
        const float xs[4] = {xv.x, xv.y, xv.z, xv.w};
#pragma unroll
        for (int jj = 0; jj < 4; ++jj) {
            float4 g0 = *(const float4*)(wg + (size_t)(j + jj) * 8);
            float4 g1 = *(const float4*)(wg + (size_t)(j + jj) * 8 + 4);
            acc[0] += xs[jj] * g0.x; acc[1] += xs[jj] * g0.y;
            acc[2] += xs[jj] * g0.z; acc[3] += xs[jj] * g0.w;
            acc[4] += xs[jj] * g1.x; acc[5] += xs[jj] * g1.y;
            acc[6] += xs[jj] * g1.z; acc[7] += xs[jj] * g1.w;
        }
    }
#pragma unroll
    for (int d = 1; d < 64; d <<= 1)
#pragma unroll
        for (int e = 0; e < 8; ++e) acc[e] += __shfl_xor(acc[e], d);

    if (lane == 0) {
        int i0 = 0; float v0 = acc[0];
#pragma unroll
        for (int e = 1; e < 8; ++e) if (acc[e] > v0) { v0 = acc[e]; i0 = e; }
        int i1 = -1; float v1 = -1e30f;
#pragma unroll
        for (int e = 0; e < 8; ++e) if (e != i0 && acc[e] > v1) { v1 = acc[e]; i1 = e; }
        float ex = __expf(v1 - v0);
        float inv = 1.f / (1.f + ex);
        topk[t * 2] = i0; topk[t * 2 + 1] = i1;
        gates[t * 2] = inv; gates[t * 2 + 1] = ex * inv;
        atomicAdd(&counts[i0], 1);
        atomicAdd(&counts[i1], 1);
    }
}

__global__ void scan_kern(const int* __restrict__ counts, int* __restrict__ offs,
                          int* __restrict__ cursors)
{
    if (threadIdx.x == 0) {
        int o = 0;
        for (int e = 0; e < NEXP; ++e) { offs[e] = o; cursors[e] = o; o += counts[e]; }
        offs[NEXP] = o;
    }
}

__global__ __launch_bounds__(256)
void scatter_kern(const int* __restrict__ topk, const float* __restrict__ gates,
                  int* __restrict__ cursors, int* __restrict__ tok_c,
                  float* __restrict__ gate_c)
{
    const int t = blockIdx.x * 256 + threadIdx.x;
#pragma unroll
    for (int k = 0; k < 2; ++k) {
        int e = topk[t * 2 + k];
        int pos = atomicAdd(&cursors[e], 1);
        tok_c[pos] = t;
        gate_c[pos] = gates[t * 2 + k];
    }
}

// ---------------- transpose + cast: [E][K][N] f32 -> [E][N][K] bf16 ----------------
__global__ __launch_bounds__(256)
void transp_kern(const float* __restrict__ in, ushort_t* __restrict__ out, int K, int N)
{
    __shared__ float tile[64][65];
    const int e = blockIdx.z;
    const size_t ibase = (size_t)e * K * N, obase = (size_t)e * N * K;
    const int k0 = blockIdx.y * 64, n0 = blockIdx.x * 64;
    const int tid = threadIdx.x;

    const int r = tid >> 4, c4 = (tid & 15) * 4;
#pragma unroll
    for (int p = 0; p < 4; ++p) {
        int kk = p * 16 + r;
        float4 v = *(const float4*)(in + ibase + (size_t)(k0 + kk) * N + n0 + c4);
        tile[kk][c4] = v.x; tile[kk][c4 + 1] = v.y; tile[kk][c4 + 2] = v.z; tile[kk][c4 + 3] = v.w;
    }
    __syncthreads();
    const int nr = tid >> 6, kc = tid & 63;
#pragma unroll
    for (int p = 0; p < 16; ++p) {
        int nn = p * 4 + nr;
        out[obase + (size_t)(n0 + nn) * K + k0 + kc] = f2bf(tile[kc][nn]);
    }
}

// ---------------- grouped GEMM, 256x256x64, 8 waves, 2-phase prefetch ----------------
// STAGE 1: A = x_bf gathered by token, relu -> h (bf16). STAGE 2: A = h, gate*y -> atomicAdd out.
// Logical block order (e-major, m, n) + bijective XCD swizzle: XCD k owns expert k's panels.
template <int STAGE, int NT, int NBLK>
__global__ __launch_bounds__(512, 1)
void gemm256(const ushort_t* __restrict__ A, const ushort_t* __restrict__ Bt,
             ushort_t* __restrict__ Hout, float* __restrict__ Out,
             const int* __restrict__ eoff, const int* __restrict__ tok_c,
             const float* __restrict__ gate_c)
{
    constexpr int K = NT * 64;
    constexpr int N = NBLK * 256;
    constexpr int MB = 32;                       // covers cnt up to 8192
    __shared__ ushort_t lds[2][2][256 * 64];     // 2 buf x {A,B} x 32KB = 128 KB

    const int nb = NEXP * MB * NBLK;
    const int orig = blockIdx.x;
    const int lg = (orig & 7) * (nb >> 3) + (orig >> 3);   // nb % 8 == 0: bijective
    const int e = lg / (MB * NBLK);
    const int rem = lg - e * (MB * NBLK);
    const int mblk = rem / NBLK;
    const int nblk = rem - mblk * NBLK;

    const int base = eoff[e];
    const int cnt = eoff[e + 1] - base;
    const int m0 = mblk * 256;
    if (m0 >= cnt) return;
    const int n0 = nblk * 256;

    const int tid = threadIdx.x;
    const int w = tid >> 6, lane = tid & 63;
    const int lhi = lane >> 4, llo = lane & 15;
    const int wm = (w >> 2) << 7;                // wave row base: 0 / 128
    const int wn = (w & 3) << 6;                 // wave col base: 0/64/128/192

    // staging: chunk ci = i*512+tid covers row r=ci>>3, 16B slot (ci&7).
    // LDS linear at ci*16; SOURCE pre-swizzled: byte-in-row ^ ((r&7)<<4)  (rule #21)
    const ushort_t* Bbase = Bt + (size_t)e * (size_t)N * (size_t)K;
    const ushort_t* asrc[4];
    const ushort_t* bsrc[4];
    int lbase[4];
#pragma unroll
    for (int i = 0; i < 4; ++i) {
        int ci = i * 512 + tid;
        int r = ci >> 3;
        int sb = ((ci & 7) << 4) ^ ((r & 7) << 4);
        int gr = m0 + r; if (gr >= cnt) gr = cnt - 1;
        size_t arow = (STAGE == 1) ? (size_t)tok_c[base + gr] * (size_t)K
                                   : (size_t)(base + gr) * (size_t)K;
        asrc[i] = A + arow + (sb >> 1);
        bsrc[i] = Bbase + (size_t)(n0 + r) * K + (sb >> 1);
        lbase[i] = (i * 8 + w) << 10;            // wave-uniform byte base
    }

    f32x4 acc[8][4];
#pragma unroll
    for (int m = 0; m < 8; ++m)
#pragma unroll
        for (int n = 0; n < 4; ++n) acc[m][n] = (f32x4)(0.f);

    // prologue
#pragma unroll
    for (int i = 0; i < 4; ++i) {
        async_load16(asrc[i], (char*)lds[0][0] + lbase[i]);
        async_load16(bsrc[i], (char*)lds[0][1] + lbase[i]);
    }
    __syncthreads();

    int cur = 0;
    for (int t = 0; t < NT; ++t) {
        if (t + 1 < NT) {
            const int k0 = (t + 1) << 6;
#pragma unroll
            for (int i = 0; i < 4; ++i) {
                async_load16(asrc[i] + k0, (char*)lds[cur ^ 1][0] + lbase[i]);
                async_load16(bsrc[i] + k0, (char*)lds[cur ^ 1][1] + lbase[i]);
            }
        }
        const char* pA = (const char*)lds[cur][0];
        const char* pB = (const char*)lds[cur][1];
#pragma unroll
        for (int ks = 0; ks < 2; ++ks) {
            const int kb = (ks << 6) + (lhi << 4);
            bfrag a[8], b[4];
#pragma unroll
            for (int m = 0; m < 8; ++m) {
                int row = wm + (m << 4) + llo;
                a[m] = *(const bfrag*)(pA + row * 128 + (kb ^ ((row & 7) << 4)));
            }
#pragma unroll
            for (int n = 0; n < 4; ++n) {
                int row = wn + (n << 4) + llo;
                b[n] = *(const bfrag*)(pB + row * 128 + (kb ^ ((row & 7) << 4)));
            }
#pragma unroll
            for (int m = 0; m < 8; ++m)
#pragma unroll
                for (int n = 0; n < 4; ++n)
                    acc[m][n] = __builtin_amdgcn_mfma_f32_16x16x32_bf16(a[m], b[n], acc[m][n], 0, 0, 0);
        }
        __syncthreads();   // drains vmcnt+lgkm: next buf ready, cur fully read
        cur ^= 1;
    }

    if (STAGE == 1) {
#pragma unroll
        for (int m = 0; m < 8; ++m)
#pragma unroll
            for (int i = 0; i < 4; ++i) {
                int row = wm + (m << 4) + (lhi << 2) + i;
                int gr = m0 + row;
                if (gr >= cnt) continue;
                size_t rb = (size_t)(base + gr) * (size_t)N + n0 + wn;
#pragma unroll
                for (int n = 0; n < 4; ++n) {
                    float v = acc[m][n][i];
                    Hout[rb + (n << 4) + llo] = f2bf(v > 0.f ? v : 0.f);
                }
            }
    } else {
#pragma unroll
        for (int m = 0; m < 8; ++m)
#pragma unroll
            for (int i = 0; i < 4; ++i) {
                int row = wm + (m << 4) + (lhi << 2) + i;
                int gr = m0 + row;
                if (gr >= cnt) continue;
                int tok = tok_c[base + gr];
                float g = gate_c[base + gr];
                size_t rb = (size_t)tok * (size_t)N + n0 + wn;
#pragma unroll
                for (int n = 0; n < 4; ++n)
                    atomicAdd(&Out[rb + (n << 4) + llo], g * acc[m][n][i]);
            }
    }
}

extern "C" void kernel_launch(void* const* d_in, const int* in_sizes, int n_in,
                              void* d_out, int out_size, void* d_ws, size_t ws_size,
                              hipStream_t stream)
{
    const float* x  = (const float*)d_in[0];   // [4,2048,1024]
    const float* wg = (const float*)d_in[1];   // [1024,8]
    const float* w1 = (const float*)d_in[2];   // [8,1024,4096]
    const float* w2 = (const float*)d_in[3];   // [8,4096,1024]
    float* out = (float*)d_out;                // [4,2048,1024] f32

    char* ws = (char*)d_ws;
    ushort_t* x_bf = (ushort_t*)(ws + 0);              // 16,777,216
    ushort_t* w1t  = (ushort_t*)(ws + 16777216);       // 67,108,864  [E][4096][1024]
    ushort_t* w2t  = (ushort_t*)(ws + 83886080);       // 67,108,864  [E][1024][4096]
    ushort_t* h    = (ushort_t*)(ws + 150994944);      // 134,217,728 [16384][4096]
    char* ctrl     = ws + 285212672;
    int*   topk    = (int*)(ctrl);
    float* gates   = (float*)(ctrl + 65536);
    int*   tok_c   = (int*)(ctrl + 131072);
    float* gate_c  = (float*)(ctrl + 196608);
    int*   counts  = (int*)(ctrl + 262144);
    int*   offs    = (int*)(ctrl + 262144 + 64);
    int*   cursors = (int*)(ctrl + 262144 + 128);

    hipMemsetAsync(counts, 0, NEXP * sizeof(int), stream);
    hipMemsetAsync(out, 0, (size_t)T_TOK * DIM * sizeof(float), stream);

    route_kern<<<T_TOK / 4, 256, 0, stream>>>(x, wg, x_bf, topk, gates, counts);
    transp_kern<<<dim3(HID / 64, DIM / 64, NEXP), 256, 0, stream>>>(w1, w1t, DIM, HID);
    transp_kern<<<dim3(DIM / 64, HID / 64, NEXP), 256, 0, stream>>>(w2, w2t, HID, DIM);
    scan_kern<<<1, 64, 0, stream>>>(counts, offs, cursors);
    scatter_kern<<<T_TOK / 256, 256, 0, stream>>>(topk, gates, cursors, tok_c, gate_c);

    // GEMM1: h = relu(x_bf[tok] @ w1t^T), K=1024 (NT=16), N=4096 (NBLK=16)
    gemm256<1, 16, 16><<<NEXP * 32 * 16, 512, 0, stream>>>(
        x_bf, w1t, h, nullptr, offs, tok_c, gate_c);
    // GEMM2: out[tok] += gate * (h @ w2t^T), K=4096 (NT=64), N=1024 (NBLK=4)
    gemm256<2, 64, 4><<<NEXP * 32 * 4, 512, 0, stream>>>(
        h, w2t, nullptr, out, offs, tok_c, gate_c);
}